// Round 5
// baseline (172.859 us; speedup 1.0000x reference)
//
#include <hip/hip_runtime.h>
#include <hip/hip_bf16.h>
#include <stdint.h>

#define NN 8192
#define FF 256

typedef unsigned short u16;
typedef __attribute__((ext_vector_type(4))) float f32x4;
typedef __attribute__((ext_vector_type(4))) unsigned int u32x4;
typedef __attribute__((ext_vector_type(8))) short s16x8;
typedef __attribute__((ext_vector_type(8))) __bf16 bf16x8;

// round-to-nearest-even f32->bf16
__device__ inline u16 f2bf_rne(float f) {
  union { float f; unsigned u; } v; v.f = f;
  unsigned r = v.u + 0x7FFFu + ((v.u >> 16) & 1u);
  return (u16)(r >> 16);
}

__device__ inline void gld_lds16(const void* g, void* l) {
  __builtin_amdgcn_global_load_lds(
      (const __attribute__((address_space(1))) void*)g,
      (__attribute__((address_space(3))) void*)l, 16, 0, 0);
}

// ---------------- K0: Wb = bf16(W), layout unchanged [o][f] ----------------
__global__ __launch_bounds__(256) void k_wb(const float* __restrict__ W,
                                            u16* __restrict__ Wb) {
  int idx = (blockIdx.x * 256 + threadIdx.x) * 4;
  f32x4 v = *reinterpret_cast<const f32x4*>(W + idx);
  ushort4 o;
  o.x = f2bf_rne(v.x); o.y = f2bf_rne(v.y); o.z = f2bf_rne(v.z); o.w = f2bf_rne(v.w);
  *reinterpret_cast<ushort4*>(Wb + idx) = o;
}

// -------- K1: per 32-row slice: rowsum -> dis; adjb = bf16(adj);
//          xwT[fo][j] = bf16(dis_j * (x @ W^T)[j][fo])  (own rows only) --------
__global__ __launch_bounds__(512) void k_pass1(const float* __restrict__ adj,
                                               const float* __restrict__ x,
                                               const u16* __restrict__ Wb,
                                               u16* __restrict__ adjb,
                                               float* __restrict__ dis,
                                               u16* __restrict__ xwT) {
  __shared__ __align__(16) u16 As[32 * 256];      // swizzled, 16 KB
  __shared__ __align__(16) u16 LT[256 * 40];      // [fo][j] pad 40, 20 KB
  __shared__ float disS[32];
  const int j0 = blockIdx.x * 32;
  const int t = threadIdx.x, lane = t & 63, w = t >> 6;

  // ---- phase A: each wave handles 4 rows: rowsum + bf16 convert ----
  for (int rr = 0; rr < 4; ++rr) {
    const int row = w * 4 + rr;
    const f32x4* p = reinterpret_cast<const f32x4*>(adj + (size_t)(j0 + row) * NN);
    u16* pb = adjb + (size_t)(j0 + row) * NN;
    float s = 0.f;
    for (int q = 0; q < 32; ++q) {
      f32x4 v = __builtin_nontemporal_load(p + q * 64 + lane);
      ushort4 o;
      o.x = f2bf_rne(v.x); o.y = f2bf_rne(v.y);
      o.z = f2bf_rne(v.z); o.w = f2bf_rne(v.w);
      *reinterpret_cast<ushort4*>(pb + (size_t)(q * 64 + lane) * 4) = o;
      s += (v.x + v.y) + (v.z + v.w);
    }
#pragma unroll
    for (int o = 32; o > 0; o >>= 1) s += __shfl_down(s, o);
    if (lane == 0) {
      float d = s > 0.f ? 1.0f / sqrtf(s) : 0.f;
      disS[row] = d;
      dis[j0 + row] = d;
    }
  }
  __syncthreads();

  // ---- phase B: stage bf16(dis_j * x[j][f]) swizzled into As ----
#pragma unroll
  for (int q = 0; q < 2; ++q) {
    int chunk = q * 512 + t;             // 0..1023
    int r = chunk >> 5, c8 = chunk & 31;
    const float* g = x + (size_t)(j0 + r) * FF + c8 * 8;
    f32x4 v0 = *reinterpret_cast<const f32x4*>(g);
    f32x4 v1 = *reinterpret_cast<const f32x4*>(g + 4);
    float d = disS[r];
    s16x8 o;
#pragma unroll
    for (int e = 0; e < 4; ++e) o[e] = (short)f2bf_rne(v0[e] * d);
#pragma unroll
    for (int e = 0; e < 4; ++e) o[4 + e] = (short)f2bf_rne(v1[e] * d);
    *reinterpret_cast<s16x8*>(&As[(r * 32 + (c8 ^ (r & 7))) * 8]) = o;
  }
  __syncthreads();

  // 8 waves (2 x 4), wave-tile 16 x 64: xw = (dis*x) @ Wb^T
  const int wr = w >> 2, wc = w & 3;
  f32x4 occ[4] = {};
#pragma unroll
  for (int ks = 0; ks < 8; ++ks) {
    int cg = ks * 4 + (lane >> 4);
    int ar = wr * 16 + (lane & 15);
    bf16x8 af = __builtin_bit_cast(bf16x8,
        *reinterpret_cast<const s16x8*>(&As[(ar * 32 + (cg ^ (ar & 7))) * 8]));
#pragma unroll
    for (int ni = 0; ni < 4; ++ni) {
      int n = wc * 64 + ni * 16 + (lane & 15);
      bf16x8 bfv = __builtin_bit_cast(bf16x8,
          *reinterpret_cast<const s16x8*>(Wb + (size_t)n * FF + cg * 8));
      occ[ni] = __builtin_amdgcn_mfma_f32_16x16x32_bf16(af, bfv, occ[ni], 0, 0, 0);
    }
  }

  // transpose through LT (pad 40 u16 -> 80 B rows, 16B-aligned halves)
  int rj0 = wr * 16 + (lane >> 4) * 4;
#pragma unroll
  for (int ni = 0; ni < 4; ++ni) {
    int c = wc * 64 + ni * 16 + (lane & 15);
#pragma unroll
    for (int e = 0; e < 4; ++e)
      LT[c * 40 + rj0 + e] = f2bf_rne(occ[ni][e]);
  }
  __syncthreads();

  // store: thread t -> fo = t>>1, 16 j's (32 B)
  {
    int fo = t >> 1, jh = (t & 1) * 16;
    const u32x4* lp = reinterpret_cast<const u32x4*>(&LT[fo * 40 + jh]);
    u32x4 a0 = lp[0], a1 = lp[1];
    u16* dst = xwT + (size_t)fo * NN + j0 + jh;
    *reinterpret_cast<u32x4*>(dst) = a0;
    *reinterpret_cast<u32x4*>(dst + 8) = a1;
  }
}

// -------- K2: out = dis_i * (adjb @ xwT^T) + bias   (direct, no split-K) --------
// BM=64 BN=128 BK=64, grid 256 (1/CU), 512 thr = 8 waves (2x4, wave 32x32).
// Decode puts the bn-pair sharing an A-panel ADJACENT ON THE SAME XCD
// (A deduped in L2 -> 128 MB HBM total), B-halves L2-windowed.
__global__ __launch_bounds__(512) void k_gemm(const u16* __restrict__ adjb,
                                              const u16* __restrict__ xwT,
                                              const float* __restrict__ dis,
                                              const float* __restrict__ bias,
                                              float* __restrict__ out) {
  __shared__ __align__(16) u16 As[2][64 * 64];    // 16 KB
  __shared__ __align__(16) u16 Bs[2][128 * 64];   // 32 KB
  const int wg = blockIdx.x;
  const int xcd = wg & 7, idx = wg >> 3;
  const int bn = idx & 1;
  const int bm = xcd * 16 + (idx >> 1);           // 0..127
  const size_t i0 = (size_t)bm * 64;
  const int n0 = bn * 128;
  const int t = threadIdx.x, lane = t & 63, w = t >> 6;
  const int wr = w >> 2, wc = w & 3;              // wave-tile 32 x 32

  f32x4 acc[2][2] = {};

  auto STAGE = [&](int buf, int kt) {
    const int kbase = kt * 64;
    // A: 64x64 bf16 = 8 KB -> 1 x 16B chunk per thread
    {
      int r = t >> 3, c8 = t & 7;
      gld_lds16(adjb + (i0 + r) * (size_t)NN + kbase + ((c8 ^ (r & 7)) * 8),
                &As[buf][t * 8]);
    }
    // B: 128x64 bf16 = 16 KB -> 2 chunks per thread
#pragma unroll
    for (int q = 0; q < 2; ++q) {
      int s = q * 512 + t;
      int n = s >> 3, c8 = s & 7;
      gld_lds16(xwT + (size_t)(n0 + n) * NN + kbase + ((c8 ^ (n & 7)) * 8),
                &Bs[buf][s * 8]);
    }
  };
  auto COMPUTE = [&](int buf) {
#pragma unroll
    for (int kk = 0; kk < 2; ++kk) {
      const int cg = kk * 4 + (lane >> 4);
      bf16x8 af[2], bfv[2];
#pragma unroll
      for (int mi = 0; mi < 2; ++mi) {
        int r = wr * 32 + mi * 16 + (lane & 15);
        af[mi] = __builtin_bit_cast(bf16x8,
            *reinterpret_cast<const s16x8*>(&As[buf][(r * 8 + (cg ^ (r & 7))) * 8]));
      }
#pragma unroll
      for (int ni = 0; ni < 2; ++ni) {
        int n = wc * 32 + ni * 16 + (lane & 15);
        bfv[ni] = __builtin_bit_cast(bf16x8,
            *reinterpret_cast<const s16x8*>(&Bs[buf][(n * 8 + (cg ^ (n & 7))) * 8]));
      }
#pragma unroll
      for (int mi = 0; mi < 2; ++mi)
#pragma unroll
        for (int ni = 0; ni < 2; ++ni)
          acc[mi][ni] = __builtin_amdgcn_mfma_f32_16x16x32_bf16(af[mi], bfv[ni], acc[mi][ni], 0, 0, 0);
    }
  };

  STAGE(0, 0);
  __syncthreads();
  for (int kt = 0; kt < 128; ++kt) {
    int buf = kt & 1;
    if (kt < 127) STAGE(buf ^ 1, kt + 1);
    COMPUTE(buf);
    __syncthreads();
  }

  // epilogue: out = acc * dis_i + bias
  int r0 = wr * 32 + (lane >> 4) * 4;
#pragma unroll
  for (int mi = 0; mi < 2; ++mi) {
#pragma unroll
    for (int e = 0; e < 4; ++e) {
      int row = (int)i0 + r0 + mi * 16 + e;
      float d = dis[row];
#pragma unroll
      for (int ni = 0; ni < 2; ++ni) {
        int col = n0 + wc * 32 + ni * 16 + (lane & 15);
        out[(size_t)row * FF + col] = acc[mi][ni][e] * d + bias[col];
      }
    }
  }
}

extern "C" void kernel_launch(void* const* d_in, const int* in_sizes, int n_in,
                              void* d_out, int out_size, void* d_ws, size_t ws_size,
                              hipStream_t stream) {
  (void)in_sizes; (void)n_in; (void)out_size; (void)ws_size;
  const float* x   = (const float*)d_in[0];
  const float* adj = (const float*)d_in[1];
  const float* W   = (const float*)d_in[2];
  const float* b   = (const float*)d_in[3];
  float* out = (float*)d_out;
  char* ws = (char*)d_ws;

  // ws: dis 32KB @0 | Wb 128KB @64KB | xwT 4MB @1MB | adjb 128MB @8MB
  float* dis  = (float*)ws;
  u16*   Wb   = (u16*)(ws + (64u << 10));
  u16*   xwT  = (u16*)(ws + (1u << 20));
  u16*   adjb = (u16*)(ws + (8u << 20));

  k_wb<<<dim3(64), dim3(256), 0, stream>>>(W, Wb);
  k_pass1<<<dim3(256), dim3(512), 0, stream>>>(adj, x, Wb, adjb, dis, xwT);
  k_gemm<<<dim3(256), dim3(512), 0, stream>>>(adjb, xwT, dis, b, out);
}

// Round 6
// 146.811 us; speedup vs baseline: 1.1774x; 1.1774x over previous
//
#include <hip/hip_runtime.h>
#include <hip/hip_bf16.h>
#include <stdint.h>

#define NN 8192
#define FF 256

typedef unsigned short u16;
typedef __attribute__((ext_vector_type(4))) float f32x4;
typedef __attribute__((ext_vector_type(4))) unsigned int u32x4;
typedef __attribute__((ext_vector_type(8))) short s16x8;
typedef __attribute__((ext_vector_type(8))) __bf16 bf16x8;

// round-to-nearest-even f32->bf16
__device__ inline u16 f2bf_rne(float f) {
  union { float f; unsigned u; } v; v.f = f;
  unsigned r = v.u + 0x7FFFu + ((v.u >> 16) & 1u);
  return (u16)(r >> 16);
}

__device__ inline void gld_lds16(const void* g, void* l) {
  __builtin_amdgcn_global_load_lds(
      (const __attribute__((address_space(1))) void*)g,
      (__attribute__((address_space(3))) void*)l, 16, 0, 0);
}

// ---------------- K0: Wb = bf16(W), layout unchanged [o][f] ----------------
__global__ __launch_bounds__(256) void k_wb(const float* __restrict__ W,
                                            u16* __restrict__ Wb) {
  int idx = (blockIdx.x * 256 + threadIdx.x) * 4;
  f32x4 v = *reinterpret_cast<const f32x4*>(W + idx);
  ushort4 o;
  o.x = f2bf_rne(v.x); o.y = f2bf_rne(v.y); o.z = f2bf_rne(v.z); o.w = f2bf_rne(v.w);
  *reinterpret_cast<ushort4*>(Wb + idx) = o;
}

// ------ K1: one row per block (high TLP): rowsum -> dis; adjb = bf16(adj) ------
// adj read is nontemporal (read-once; keep L3 for adjb which k_gemm re-reads).
__global__ __launch_bounds__(256) void k_pass1(const float* __restrict__ adj,
                                               u16* __restrict__ adjb,
                                               float* __restrict__ dis) {
  const int row = blockIdx.x;
  const int t = threadIdx.x;
  const f32x4* p = reinterpret_cast<const f32x4*>(adj + (size_t)row * NN);
  u16* pb = adjb + (size_t)row * NN;
  float s = 0.f;
#pragma unroll
  for (int q = 0; q < 4; ++q) {
    int c2 = q * 256 + t;                 // 32B chunk id, 0..1023
    f32x4 v0 = __builtin_nontemporal_load(p + c2 * 2);
    f32x4 v1 = __builtin_nontemporal_load(p + c2 * 2 + 1);
    s16x8 o;
#pragma unroll
    for (int e = 0; e < 4; ++e) o[e] = (short)f2bf_rne(v0[e]);
#pragma unroll
    for (int e = 0; e < 4; ++e) o[4 + e] = (short)f2bf_rne(v1[e]);
    *reinterpret_cast<s16x8*>(pb + c2 * 8) = o;
    s += ((v0.x + v0.y) + (v0.z + v0.w)) + ((v1.x + v1.y) + (v1.z + v1.w));
  }
#pragma unroll
  for (int o = 32; o > 0; o >>= 1) s += __shfl_down(s, o);
  __shared__ float red[4];
  if ((t & 63) == 0) red[t >> 6] = s;
  __syncthreads();
  if (t == 0) {
    float tot = (red[0] + red[1]) + (red[2] + red[3]);
    dis[row] = tot > 0.f ? 1.0f / sqrtf(tot) : 0.f;
  }
}

// ------- K2: xwT[fo][j] = bf16( dis[j] * (x @ W^T)[j][fo] )  (transposed) -------
// (R4-verified) block: 32 j-rows x 256 fo, 4 waves.
__global__ __launch_bounds__(256) void k_xwt(const float* __restrict__ x,
                                             const float* __restrict__ dis,
                                             const u16* __restrict__ Wb,
                                             u16* __restrict__ xwT) {
  __shared__ __align__(16) u16 As[32 * 256];     // slot = r*32 + (c8^(r&7))
  __shared__ __align__(16) u16 LT[256 * 34];     // [fo][j], pad 34
  const int j0 = blockIdx.x * 32;
  const int t = threadIdx.x, lane = t & 63, w = t >> 6;
  const int wr = w >> 1, wc = w & 1;

#pragma unroll
  for (int q = 0; q < 4; ++q) {
    int chunk = t * 4 + q;           // 0..1023
    int r = chunk >> 5, c8 = chunk & 31;
    const float* g = x + (size_t)(j0 + r) * FF + c8 * 8;
    f32x4 v0 = *reinterpret_cast<const f32x4*>(g);
    f32x4 v1 = *reinterpret_cast<const f32x4*>(g + 4);
    float d = dis[j0 + r];
    s16x8 o;
#pragma unroll
    for (int e = 0; e < 4; ++e) o[e] = (short)f2bf_rne(v0[e] * d);
#pragma unroll
    for (int e = 0; e < 4; ++e) o[4 + e] = (short)f2bf_rne(v1[e] * d);
    *reinterpret_cast<s16x8*>(&As[(r * 32 + (c8 ^ (r & 7))) * 8]) = o;
  }
  __syncthreads();

  f32x4 occ[8] = {};
#pragma unroll
  for (int ks = 0; ks < 8; ++ks) {
    int cg = ks * 4 + (lane >> 4);
    int ar = wr * 16 + (lane & 15);
    bf16x8 af = __builtin_bit_cast(bf16x8,
        *reinterpret_cast<const s16x8*>(&As[(ar * 32 + (cg ^ (ar & 7))) * 8]));
#pragma unroll
    for (int ni = 0; ni < 8; ++ni) {
      int n = wc * 128 + ni * 16 + (lane & 15);
      bf16x8 bfv = __builtin_bit_cast(bf16x8,
          *reinterpret_cast<const s16x8*>(Wb + (size_t)n * FF + cg * 8));
      occ[ni] = __builtin_amdgcn_mfma_f32_16x16x32_bf16(af, bfv, occ[ni], 0, 0, 0);
    }
  }

  int rj0 = wr * 16 + (lane >> 4) * 4;
#pragma unroll
  for (int ni = 0; ni < 8; ++ni) {
    int c = wc * 128 + ni * 16 + (lane & 15);
#pragma unroll
    for (int e = 0; e < 4; ++e)
      LT[c * 34 + rj0 + e] = f2bf_rne(occ[ni][e]);
  }
  __syncthreads();

  {
    int fo = t, base = fo * 34;
    u16* dst = xwT + (size_t)fo * NN + j0;
#pragma unroll
    for (int q = 0; q < 4; ++q) {
      ushort4 vv;
      vv.x = LT[base + q * 8 + 0]; vv.y = LT[base + q * 8 + 1];
      vv.z = LT[base + q * 8 + 2]; vv.w = LT[base + q * 8 + 3];
      ushort4 vw;
      vw.x = LT[base + q * 8 + 4]; vw.y = LT[base + q * 8 + 5];
      vw.z = LT[base + q * 8 + 6]; vw.w = LT[base + q * 8 + 7];
      *reinterpret_cast<ushort4*>(dst + q * 8) = vv;
      *reinterpret_cast<ushort4*>(dst + q * 8 + 4) = vw;
    }
  }
}

// -------- K3: out = dis_i * (adjb @ xwT^T) + bias  (full K, direct out) --------
// BM=64 BN=64 BK=128, grid 512 (2 blocks/CU), 256 thr = 4 waves (2x2, 32x32).
// XCD decode: the 4 bn-blocks of one bm are consecutive slots on ONE XCD ->
// A-panel read once into that XCD's L2. B (xwT, 4MB) is L3-resident.
__global__ __launch_bounds__(256) void k_gemm(const u16* __restrict__ adjb,
                                              const u16* __restrict__ xwT,
                                              const float* __restrict__ dis,
                                              const float* __restrict__ bias,
                                              float* __restrict__ out) {
  __shared__ __align__(16) u16 As[2][64 * 128];   // 16 KB x2
  __shared__ __align__(16) u16 Bs[2][64 * 128];   // 16 KB x2
  const int wg = blockIdx.x;
  const int xcd = wg & 7, s = wg >> 3;
  const int bn = s & 3;
  const int bm = (s >> 2) * 8 + xcd;              // 0..127
  const size_t i0 = (size_t)bm * 64;
  const int n0 = bn * 64;
  const int t = threadIdx.x, lane = t & 63, w = t >> 6;
  const int wr = w >> 1, wc = w & 1;              // wave-tile 32 x 32

  f32x4 acc[2][2] = {};

  // rows of 128 u16 = 16 chunks of 16B; swizzle chunk col: cg ^ (r & 15)
  auto STAGE = [&](int buf, int kt) {
    const int kbase = kt * 128;
#pragma unroll
    for (int q = 0; q < 4; ++q) {
      int c = q * 256 + t;                  // chunk id 0..1023
      int r = c >> 4, cg = (c & 15) ^ (r & 15);
      gld_lds16(adjb + (i0 + r) * (size_t)NN + kbase + cg * 8,
                &As[buf][c * 8]);
    }
#pragma unroll
    for (int q = 0; q < 4; ++q) {
      int c = q * 256 + t;
      int r = c >> 4, cg = (c & 15) ^ (r & 15);
      gld_lds16(xwT + (size_t)(n0 + r) * NN + kbase + cg * 8,
                &Bs[buf][c * 8]);
    }
  };
  auto COMPUTE = [&](int buf) {
#pragma unroll
    for (int kk = 0; kk < 4; ++kk) {
      const int cg = kk * 4 + (lane >> 4);
      bf16x8 af[2], bfv[2];
#pragma unroll
      for (int mi = 0; mi < 2; ++mi) {
        int r = wr * 32 + mi * 16 + (lane & 15);
        af[mi] = __builtin_bit_cast(bf16x8,
            *reinterpret_cast<const s16x8*>(&As[buf][(r * 16 + (cg ^ (r & 15))) * 8]));
      }
#pragma unroll
      for (int ni = 0; ni < 2; ++ni) {
        int n = wc * 32 + ni * 16 + (lane & 15);
        bfv[ni] = __builtin_bit_cast(bf16x8,
            *reinterpret_cast<const s16x8*>(&Bs[buf][(n * 16 + (cg ^ (n & 15))) * 8]));
      }
#pragma unroll
      for (int mi = 0; mi < 2; ++mi)
#pragma unroll
        for (int ni = 0; ni < 2; ++ni)
          acc[mi][ni] = __builtin_amdgcn_mfma_f32_16x16x32_bf16(af[mi], bfv[ni], acc[mi][ni], 0, 0, 0);
    }
  };

  STAGE(0, 0);
  __syncthreads();
  for (int kt = 0; kt < 64; ++kt) {
    int buf = kt & 1;
    if (kt < 63) STAGE(buf ^ 1, kt + 1);
    COMPUTE(buf);
    __syncthreads();
  }

  // epilogue: out = acc * dis_i + bias
  int r0 = wr * 32 + (lane >> 4) * 4;
#pragma unroll
  for (int mi = 0; mi < 2; ++mi) {
#pragma unroll
    for (int e = 0; e < 4; ++e) {
      int row = (int)i0 + r0 + mi * 16 + e;
      float d = dis[row];
#pragma unroll
      for (int ni = 0; ni < 2; ++ni) {
        int col = n0 + wc * 32 + ni * 16 + (lane & 15);
        out[(size_t)row * FF + col] = acc[mi][ni][e] * d + bias[col];
      }
    }
  }
}

extern "C" void kernel_launch(void* const* d_in, const int* in_sizes, int n_in,
                              void* d_out, int out_size, void* d_ws, size_t ws_size,
                              hipStream_t stream) {
  (void)in_sizes; (void)n_in; (void)out_size; (void)ws_size;
  const float* x   = (const float*)d_in[0];
  const float* adj = (const float*)d_in[1];
  const float* W   = (const float*)d_in[2];
  const float* b   = (const float*)d_in[3];
  float* out = (float*)d_out;
  char* ws = (char*)d_ws;

  // ws: dis 32KB @0 | Wb 128KB @64KB | xwT 4MB @1MB | adjb 128MB @8MB
  float* dis  = (float*)ws;
  u16*   Wb   = (u16*)(ws + (64u << 10));
  u16*   xwT  = (u16*)(ws + (1u << 20));
  u16*   adjb = (u16*)(ws + (8u << 20));

  k_wb<<<dim3(64), dim3(256), 0, stream>>>(W, Wb);
  k_pass1<<<dim3(8192), dim3(256), 0, stream>>>(adj, adjb, dis);
  k_xwt<<<dim3(256), dim3(256), 0, stream>>>(x, dis, Wb, xwT);
  k_gemm<<<dim3(512), dim3(256), 0, stream>>>(adjb, xwT, dis, b, out);
}